// Round 1
// baseline (690.383 us; speedup 1.0000x reference)
//
#include <hip/hip_runtime.h>
#include <stdint.h>

// Problem constants (fixed by setup_inputs)
#define B_N   8
#define S_N   2048
#define D_N   1024
#define A_N   512
#define DV_N  512

typedef __attribute__((ext_vector_type(8))) short bf16x8;
typedef __attribute__((ext_vector_type(4))) float f32x4;

__device__ __forceinline__ unsigned short f2bf(float x) {
    union { float f; unsigned int u; } v; v.f = x;
    return (unsigned short)((v.u + 0x7fffu + ((v.u >> 16) & 1u)) >> 16);
}

__global__ void cvt_f32_bf16(const float* __restrict__ src,
                             unsigned short* __restrict__ dst, int n4) {
    int i = blockIdx.x * blockDim.x + threadIdx.x;
    if (i >= n4) return;
    float4 v = ((const float4*)src)[i];
    ushort4 o;
    o.x = f2bf(v.x); o.y = f2bf(v.y); o.z = f2bf(v.z); o.w = f2bf(v.w);
    ((ushort4*)dst)[i] = o;
}

__device__ __forceinline__ void gld_lds16(const void* g, void* l) {
    __builtin_amdgcn_global_load_lds(
        (const __attribute__((address_space(1))) unsigned int*)g,
        (__attribute__((address_space(3))) unsigned int*)l, 16, 0, 0);
}

// NT GEMM: C[m,n] = sum_k A[m,k]*B[n,k]  (A: MxK bf16 row-major, B: NxK bf16 row-major)
// 128x128 block tile, BK=32, 4 waves in 2x2, each wave 4x4 frags of 16x16x32 MFMA.
// MODE 0: bf16 out, + bias[col]              (Q/K projections)
// MODE 1: bf16 out, + bias[row]              (WV^T projection: rows = Dv)
// MODE 2: f32 out,  * scale + mask[b][col][row] * -1e9   (scores^T, written to d_out attn region)
// MODE 3: f32 out                             (final attn @ WV)
template <int MODE>
__global__ __launch_bounds__(256) void gemm_nt(
    const unsigned short* __restrict__ A, const unsigned short* __restrict__ B,
    void* __restrict__ C, const float* __restrict__ bias,
    const int* __restrict__ mask, int M, int N, int K,
    long long sA, long long sB, long long sC, float scale)
{
    __shared__ __align__(16) unsigned short As[128 * 32];
    __shared__ __align__(16) unsigned short Bs[128 * 32];

    const int tid  = threadIdx.x;
    const int wave = tid >> 6;
    const int lane = tid & 63;
    const int lrow = lane & 15;
    const int quad = lane >> 4;
    const int wm = wave & 1;   // wave row (0..1) -> 64 rows each
    const int wn = wave >> 1;  // wave col (0..1) -> 64 cols each
    const int b  = blockIdx.z;
    const int m0 = blockIdx.y * 128;
    const int n0 = blockIdx.x * 128;

    const unsigned short* Ab = A + (long long)b * sA;
    const unsigned short* Bb = B + (long long)b * sB;

    f32x4 acc[4][4];
#pragma unroll
    for (int i = 0; i < 4; ++i)
#pragma unroll
        for (int j = 0; j < 4; ++j) acc[i][j] = (f32x4){0.f, 0.f, 0.f, 0.f};

    // staging addressing: each wave moves 2 x 1KB segments per tile (16 rows x 64B each),
    // lane l supplies the global 16B chunk that lands at wave_base + l*16 in LDS.
    const int srow = lane >> 2;        // row within 16-row segment
    const int scol = (lane & 3) * 8;   // k-element offset (8 bf16 = 16B)

    for (int kt = 0; kt < K; kt += 32) {
#pragma unroll
        for (int t = 0; t < 2; ++t) {
            const int seg = t * 4 + wave;  // 0..7
            const unsigned short* ga =
                Ab + (long long)(m0 + seg * 16 + srow) * K + kt + scol;
            gld_lds16(ga, &As[seg * 16 * 32]);
            const unsigned short* gb =
                Bb + (long long)(n0 + seg * 16 + srow) * K + kt + scol;
            gld_lds16(gb, &Bs[seg * 16 * 32]);
        }
        __syncthreads();

        bf16x8 af[4], bfr[4];
#pragma unroll
        for (int i = 0; i < 4; ++i)
            af[i] = *(const bf16x8*)&As[(wm * 64 + i * 16 + lrow) * 32 + quad * 8];
#pragma unroll
        for (int j = 0; j < 4; ++j)
            bfr[j] = *(const bf16x8*)&Bs[(wn * 64 + j * 16 + lrow) * 32 + quad * 8];
#pragma unroll
        for (int i = 0; i < 4; ++i)
#pragma unroll
            for (int j = 0; j < 4; ++j)
                acc[i][j] = __builtin_amdgcn_mfma_f32_16x16x32_bf16(
                    af[i], bfr[j], acc[i][j], 0, 0, 0);
        __syncthreads();
    }

    // Epilogue. C/D layout (verified): col = lane&15, row = quad*4 + reg.
#pragma unroll
    for (int i = 0; i < 4; ++i) {
        const int rowb = m0 + wm * 64 + i * 16 + quad * 4;
#pragma unroll
        for (int j = 0; j < 4; ++j) {
            const int col = n0 + wn * 64 + j * 16 + lrow;
#pragma unroll
            for (int r = 0; r < 4; ++r) {
                const int row = rowb + r;
                float v = acc[i][j][r];
                if (MODE == 0) {
                    v += bias[col];
                    ((unsigned short*)C)[(long long)row * N + col] = f2bf(v);
                } else if (MODE == 1) {
                    v += bias[row];
                    (((unsigned short*)C) + (long long)b * sC)
                        [(long long)row * N + col] = f2bf(v);
                } else if (MODE == 2) {
                    v *= scale;
                    const int mv = mask[(long long)b * S_N * S_N +
                                        (long long)col * S_N + row];
                    v += (float)mv * -1e9f;
                    (((float*)C) + (long long)b * sC)[(long long)row * N + col] = v;
                } else {
                    (((float*)C) + (long long)b * sC)[(long long)row * N + col] = v;
                }
            }
        }
    }
}

// Row softmax over contiguous rows of length 2048 (the q axis of scores^T),
// in-place fp32 (d_out attn region) + bf16 copy for the final GEMM.
__global__ __launch_bounds__(256) void softmax_rows(
    float* __restrict__ sT, unsigned short* __restrict__ pbf)
{
    const long long row = blockIdx.x;
    float* p = sT + row * S_N;
    unsigned short* q = pbf + row * S_N;
    const int tid = threadIdx.x;
    const int wave = tid >> 6, lane = tid & 63;

    float4 v0 = ((const float4*)p)[tid];
    float4 v1 = ((const float4*)p)[tid + 256];

    float mx = fmaxf(fmaxf(fmaxf(v0.x, v0.y), fmaxf(v0.z, v0.w)),
                     fmaxf(fmaxf(v1.x, v1.y), fmaxf(v1.z, v1.w)));
#pragma unroll
    for (int off = 32; off; off >>= 1) mx = fmaxf(mx, __shfl_xor(mx, off));

    __shared__ float redm[4];
    __shared__ float reds[4];
    if (lane == 0) redm[wave] = mx;
    __syncthreads();
    mx = fmaxf(fmaxf(redm[0], redm[1]), fmaxf(redm[2], redm[3]));

    float e[8];
    e[0] = __expf(v0.x - mx); e[1] = __expf(v0.y - mx);
    e[2] = __expf(v0.z - mx); e[3] = __expf(v0.w - mx);
    e[4] = __expf(v1.x - mx); e[5] = __expf(v1.y - mx);
    e[6] = __expf(v1.z - mx); e[7] = __expf(v1.w - mx);

    float sum = e[0] + e[1] + e[2] + e[3] + e[4] + e[5] + e[6] + e[7];
#pragma unroll
    for (int off = 32; off; off >>= 1) sum += __shfl_xor(sum, off);
    if (lane == 0) reds[wave] = sum;
    __syncthreads();
    sum = reds[0] + reds[1] + reds[2] + reds[3];
    const float inv = 1.0f / sum;

    float4 o0 = {e[0] * inv, e[1] * inv, e[2] * inv, e[3] * inv};
    float4 o1 = {e[4] * inv, e[5] * inv, e[6] * inv, e[7] * inv};
    ((float4*)p)[tid]       = o0;
    ((float4*)p)[tid + 256] = o1;
    ushort4 b0 = {f2bf(o0.x), f2bf(o0.y), f2bf(o0.z), f2bf(o0.w)};
    ushort4 b1 = {f2bf(o1.x), f2bf(o1.y), f2bf(o1.z), f2bf(o1.w)};
    ((ushort4*)q)[tid]       = b0;
    ((ushort4*)q)[tid + 256] = b1;
}

extern "C" void kernel_launch(void* const* d_in, const int* in_sizes, int n_in,
                              void* d_out, int out_size, void* d_ws, size_t ws_size,
                              hipStream_t stream) {
    const float* Q    = (const float*)d_in[0];
    const float* K    = (const float*)d_in[1];
    const float* V    = (const float*)d_in[2];
    const int*   mask = (const int*)d_in[3];
    const float* Wq   = (const float*)d_in[4];
    const float* bq   = (const float*)d_in[5];
    const float* Wk   = (const float*)d_in[6];
    const float* bk   = (const float*)d_in[7];
    const float* Wv   = (const float*)d_in[8];
    const float* bv   = (const float*)d_in[9];

    float* out      = (float*)d_out;                              // [B,S,Dv]
    float* attn_out = out + (long long)B_N * S_N * DV_N;          // [B,S,S] (k-major rows over q)

    // Workspace layout (peak ~147 MB). Qbf+Kbf (67.1MB) are dead after the
    // scores GEMM and get overlaid by attn_bf (exactly 67.1MB).
    unsigned short* Qbf  = (unsigned short*)d_ws;
    unsigned short* Kbf  = Qbf + (long long)B_N * S_N * D_N;
    unsigned short* attn_bf = Qbf;  // overlay
    unsigned short* Vbf  = Kbf + (long long)B_N * S_N * D_N;
    unsigned short* Wqbf = Vbf + (long long)B_N * S_N * D_N;
    unsigned short* Wkbf = Wqbf + (long long)A_N * D_N;
    unsigned short* Wvbf = Wkbf + (long long)A_N * D_N;
    unsigned short* Qp   = Wvbf + (long long)DV_N * D_N;
    unsigned short* Kp   = Qp + (long long)B_N * S_N * A_N;
    unsigned short* WVt  = Kp + (long long)B_N * S_N * A_N;

    const float scale = 0.044194173824159216f;  // 1/sqrt(512)

    // 1) fp32 -> bf16 conversions
    {
        long long nQ = (long long)B_N * S_N * D_N;
        long long nW = (long long)A_N * D_N;
        int n4;
        n4 = (int)(nQ / 4);
        cvt_f32_bf16<<<dim3((n4 + 255) / 256), dim3(256), 0, stream>>>(Q, Qbf, n4);
        cvt_f32_bf16<<<dim3((n4 + 255) / 256), dim3(256), 0, stream>>>(K, Kbf, n4);
        cvt_f32_bf16<<<dim3((n4 + 255) / 256), dim3(256), 0, stream>>>(V, Vbf, n4);
        n4 = (int)(nW / 4);
        cvt_f32_bf16<<<dim3((n4 + 255) / 256), dim3(256), 0, stream>>>(Wq, Wqbf, n4);
        cvt_f32_bf16<<<dim3((n4 + 255) / 256), dim3(256), 0, stream>>>(Wk, Wkbf, n4);
        cvt_f32_bf16<<<dim3((n4 + 255) / 256), dim3(256), 0, stream>>>(Wv, Wvbf, n4);
    }

    // 2) Qp = Q @ Wq^T + bq   [16384 x 512] bf16
    gemm_nt<0><<<dim3(A_N / 128, (B_N * S_N) / 128, 1), dim3(256), 0, stream>>>(
        Qbf, Wqbf, (void*)Qp, bq, nullptr, B_N * S_N, A_N, D_N, 0, 0, 0, 1.0f);
    // 3) Kp = K @ Wk^T + bk
    gemm_nt<0><<<dim3(A_N / 128, (B_N * S_N) / 128, 1), dim3(256), 0, stream>>>(
        Kbf, Wkbf, (void*)Kp, bk, nullptr, B_N * S_N, A_N, D_N, 0, 0, 0, 1.0f);
    // 4) WVt[b] = (V[b] @ Wv^T + bv)^T : M=Dv rows, N=S cols
    gemm_nt<1><<<dim3(S_N / 128, DV_N / 128, B_N), dim3(256), 0, stream>>>(
        Wvbf, Vbf, (void*)WVt, bv, nullptr, DV_N, S_N, D_N,
        0, (long long)S_N * D_N, (long long)DV_N * S_N, 1.0f);
    // 5) scores^T[b,k,q] = (Kp[b,k,:].Qp[b,q,:])*scale + mask[b,q,k]*-1e9 -> d_out attn region
    gemm_nt<2><<<dim3(S_N / 128, S_N / 128, B_N), dim3(256), 0, stream>>>(
        Kp, Qp, (void*)attn_out, nullptr, mask, S_N, S_N, A_N,
        (long long)S_N * A_N, (long long)S_N * A_N, (long long)S_N * S_N, scale);
    // 6) row softmax over q (in place) + bf16 copy
    softmax_rows<<<dim3(B_N * S_N), dim3(256), 0, stream>>>(attn_out, attn_bf);
    // 7) selfOutput[b,k,v] = sum_q attn[b,k,q] * WVt[b,v,q]
    gemm_nt<3><<<dim3(DV_N / 128, S_N / 128, B_N), dim3(256), 0, stream>>>(
        attn_bf, WVt, (void*)out, nullptr, nullptr, S_N, DV_N, S_N,
        (long long)S_N * S_N, (long long)DV_N * S_N, (long long)S_N * DV_N, 1.0f);
}

// Round 2
// 686.568 us; speedup vs baseline: 1.0056x; 1.0056x over previous
//
#include <hip/hip_runtime.h>
#include <stdint.h>

// Problem constants (fixed by setup_inputs)
#define B_N   8
#define S_N   2048
#define D_N   1024
#define A_N   512
#define DV_N  512

typedef __attribute__((ext_vector_type(8))) short bf16x8;
typedef __attribute__((ext_vector_type(4))) float f32x4;

__device__ __forceinline__ unsigned short f2bf(float x) {
    union { float f; unsigned int u; } v; v.f = x;
    return (unsigned short)((v.u + 0x7fffu + ((v.u >> 16) & 1u)) >> 16);
}

__global__ void cvt_f32_bf16(const float* __restrict__ src,
                             unsigned short* __restrict__ dst, int n4) {
    int i = blockIdx.x * blockDim.x + threadIdx.x;
    if (i >= n4) return;
    float4 v = ((const float4*)src)[i];
    ushort4 o;
    o.x = f2bf(v.x); o.y = f2bf(v.y); o.z = f2bf(v.z); o.w = f2bf(v.w);
    ((ushort4*)dst)[i] = o;
}

__device__ __forceinline__ void gld_lds16(const void* g, void* l) {
    __builtin_amdgcn_global_load_lds(
        (const __attribute__((address_space(1))) unsigned int*)g,
        (__attribute__((address_space(3))) unsigned int*)l, 16, 0, 0);
}

// Bit-pack the transposed mask: mpT[b][k][w] bit q%32 of word q/32 = mask[b][q][k].
// Tile: 64 q x 128 k per block. Coalesced int4 loads -> LDS (row stride 129 ints,
// odd stride => conflict-free column reads) -> per-k ballot over 64 q-lanes.
__global__ __launch_bounds__(256) void pack_maskT(const int* __restrict__ mask,
                                                  unsigned int* __restrict__ mpT) {
    __shared__ int tile[64 * 129];
    const int b  = blockIdx.z;
    const int q0 = blockIdx.y * 64;
    const int k0 = blockIdx.x * 128;
    const int tid = threadIdx.x;
    const long long base = (long long)b * S_N * S_N;
#pragma unroll
    for (int it = 0; it < 8; ++it) {
        int c = it * 256 + tid;          // 0..2047 chunk id (4 ints each)
        int row  = c >> 5;               // q within tile
        int col4 = (c & 31) * 4;         // k within tile
        int4 v = *(const int4*)&mask[base + (long long)(q0 + row) * S_N + k0 + col4];
        int* d = &tile[row * 129 + col4];
        d[0] = v.x; d[1] = v.y; d[2] = v.z; d[3] = v.w;
    }
    __syncthreads();
    const int wave = tid >> 6, lane = tid & 63;
#pragma unroll
    for (int kk = 0; kk < 32; ++kk) {
        const int k = wave * 32 + kk;
        const int v = tile[lane * 129 + k];       // bank = (lane+k)%32, 2-way = free
        const unsigned long long bal = __ballot(v != 0);
        if (lane == 0) {
            unsigned int* o = &mpT[(long long)(b * S_N + k0 + k) * 64 + (q0 >> 5)];
            o[0] = (unsigned int)bal;
            o[1] = (unsigned int)(bal >> 32);
        }
    }
}

// NT GEMM: C[m,n] = sum_k A[m,k]*B[n,k]  (A: MxK bf16 row-major, B: NxK bf16 row-major)
// 128x128 block tile, BK=32, 4 waves in 2x2, each wave 4x4 frags of 16x16x32 MFMA.
// MODE 0: bf16 out, + bias[col]              (Q/K projections)
// MODE 1: bf16 out, + bias[row]              (WV^T projection: rows = Dv)
// MODE 2: f32 out,  * scale                  (scores^T, mask applied later in softmax)
// MODE 3: f32 out                             (final attn @ WV)
template <int MODE>
__global__ __launch_bounds__(256) void gemm_nt(
    const unsigned short* __restrict__ A, const unsigned short* __restrict__ B,
    void* __restrict__ C, const float* __restrict__ bias,
    int M, int N, int K,
    long long sA, long long sB, long long sC, float scale)
{
    __shared__ __align__(16) unsigned short As[128 * 32];
    __shared__ __align__(16) unsigned short Bs[128 * 32];

    const int tid  = threadIdx.x;
    const int wave = tid >> 6;
    const int lane = tid & 63;
    const int lrow = lane & 15;
    const int quad = lane >> 4;
    const int wm = wave & 1;   // wave row (0..1) -> 64 rows each
    const int wn = wave >> 1;  // wave col (0..1) -> 64 cols each
    const int b  = blockIdx.z;
    const int m0 = blockIdx.y * 128;
    const int n0 = blockIdx.x * 128;

    const unsigned short* Ab = A + (long long)b * sA;
    const unsigned short* Bb = B + (long long)b * sB;

    f32x4 acc[4][4];
#pragma unroll
    for (int i = 0; i < 4; ++i)
#pragma unroll
        for (int j = 0; j < 4; ++j) acc[i][j] = (f32x4){0.f, 0.f, 0.f, 0.f};

    // staging: each wave moves 2 x 1KB segments per tile (16 rows x 64B each),
    // lane l supplies the global 16B chunk that lands at wave_base + l*16 in LDS.
    const int srow = lane >> 2;        // row within 16-row segment
    const int scol = (lane & 3) * 8;   // k-element offset (8 bf16 = 16B)

    for (int kt = 0; kt < K; kt += 32) {
#pragma unroll
        for (int t = 0; t < 2; ++t) {
            const int seg = t * 4 + wave;  // 0..7
            const unsigned short* ga =
                Ab + (long long)(m0 + seg * 16 + srow) * K + kt + scol;
            gld_lds16(ga, &As[seg * 16 * 32]);
            const unsigned short* gb =
                Bb + (long long)(n0 + seg * 16 + srow) * K + kt + scol;
            gld_lds16(gb, &Bs[seg * 16 * 32]);
        }
        __syncthreads();

        bf16x8 af[4], bfr[4];
#pragma unroll
        for (int i = 0; i < 4; ++i)
            af[i] = *(const bf16x8*)&As[(wm * 64 + i * 16 + lrow) * 32 + quad * 8];
#pragma unroll
        for (int j = 0; j < 4; ++j)
            bfr[j] = *(const bf16x8*)&Bs[(wn * 64 + j * 16 + lrow) * 32 + quad * 8];
#pragma unroll
        for (int i = 0; i < 4; ++i)
#pragma unroll
            for (int j = 0; j < 4; ++j)
                acc[i][j] = __builtin_amdgcn_mfma_f32_16x16x32_bf16(
                    af[i], bfr[j], acc[i][j], 0, 0, 0);
        __syncthreads();
    }

    // Epilogue. C/D layout (verified): col = lane&15, row = quad*4 + reg.
#pragma unroll
    for (int i = 0; i < 4; ++i) {
        const int rowb = m0 + wm * 64 + i * 16 + quad * 4;
#pragma unroll
        for (int j = 0; j < 4; ++j) {
            const int col = n0 + wn * 64 + j * 16 + lrow;
#pragma unroll
            for (int r = 0; r < 4; ++r) {
                const int row = rowb + r;
                float v = acc[i][j][r];
                if (MODE == 0) {
                    v += bias[col];
                    ((unsigned short*)C)[(long long)row * N + col] = f2bf(v);
                } else if (MODE == 1) {
                    v += bias[row];
                    (((unsigned short*)C) + (long long)b * sC)
                        [(long long)row * N + col] = f2bf(v);
                } else if (MODE == 2) {
                    v *= scale;
                    (((float*)C) + (long long)b * sC)[(long long)row * N + col] = v;
                } else {
                    (((float*)C) + (long long)b * sC)[(long long)row * N + col] = v;
                }
            }
        }
    }
}

// Row softmax over contiguous rows of length 2048 (the q axis of scores^T),
// applying the bit-packed transposed mask (-1e9 where bit set), in-place fp32
// (d_out attn region) + bf16 copy for the final GEMM.
__global__ __launch_bounds__(256) void softmax_rows(
    float* __restrict__ sT, unsigned short* __restrict__ pbf,
    const unsigned int* __restrict__ mpT)
{
    const long long row = blockIdx.x;
    float* p = sT + row * S_N;
    unsigned short* q = pbf + row * S_N;
    const int tid = threadIdx.x;
    const int wave = tid >> 6, lane = tid & 63;

    float4 v0 = ((const float4*)p)[tid];
    float4 v1 = ((const float4*)p)[tid + 256];

    // mask bits: q-index tid*4.. in word tid/8; q2 = 1024+tid*4 in word 32+tid/8
    const unsigned int* mp = mpT + row * 64;
    const unsigned int w0 = mp[tid >> 3];
    const unsigned int w1 = mp[32 + (tid >> 3)];
    const int sh = (tid & 7) * 4;
    v0.x += ((w0 >> (sh + 0)) & 1u) ? -1e9f : 0.0f;
    v0.y += ((w0 >> (sh + 1)) & 1u) ? -1e9f : 0.0f;
    v0.z += ((w0 >> (sh + 2)) & 1u) ? -1e9f : 0.0f;
    v0.w += ((w0 >> (sh + 3)) & 1u) ? -1e9f : 0.0f;
    v1.x += ((w1 >> (sh + 0)) & 1u) ? -1e9f : 0.0f;
    v1.y += ((w1 >> (sh + 1)) & 1u) ? -1e9f : 0.0f;
    v1.z += ((w1 >> (sh + 2)) & 1u) ? -1e9f : 0.0f;
    v1.w += ((w1 >> (sh + 3)) & 1u) ? -1e9f : 0.0f;

    float mx = fmaxf(fmaxf(fmaxf(v0.x, v0.y), fmaxf(v0.z, v0.w)),
                     fmaxf(fmaxf(v1.x, v1.y), fmaxf(v1.z, v1.w)));
#pragma unroll
    for (int off = 32; off; off >>= 1) mx = fmaxf(mx, __shfl_xor(mx, off));

    __shared__ float redm[4];
    __shared__ float reds[4];
    if (lane == 0) redm[wave] = mx;
    __syncthreads();
    mx = fmaxf(fmaxf(redm[0], redm[1]), fmaxf(redm[2], redm[3]));

    float e[8];
    e[0] = __expf(v0.x - mx); e[1] = __expf(v0.y - mx);
    e[2] = __expf(v0.z - mx); e[3] = __expf(v0.w - mx);
    e[4] = __expf(v1.x - mx); e[5] = __expf(v1.y - mx);
    e[6] = __expf(v1.z - mx); e[7] = __expf(v1.w - mx);

    float sum = e[0] + e[1] + e[2] + e[3] + e[4] + e[5] + e[6] + e[7];
#pragma unroll
    for (int off = 32; off; off >>= 1) sum += __shfl_xor(sum, off);
    if (lane == 0) reds[wave] = sum;
    __syncthreads();
    sum = reds[0] + reds[1] + reds[2] + reds[3];
    const float inv = 1.0f / sum;

    float4 o0 = {e[0] * inv, e[1] * inv, e[2] * inv, e[3] * inv};
    float4 o1 = {e[4] * inv, e[5] * inv, e[6] * inv, e[7] * inv};
    ((float4*)p)[tid]       = o0;
    ((float4*)p)[tid + 256] = o1;
    ushort4 b0 = {f2bf(o0.x), f2bf(o0.y), f2bf(o0.z), f2bf(o0.w)};
    ushort4 b1 = {f2bf(o1.x), f2bf(o1.y), f2bf(o1.z), f2bf(o1.w)};
    ((ushort4*)q)[tid]       = b0;
    ((ushort4*)q)[tid + 256] = b1;
}

extern "C" void kernel_launch(void* const* d_in, const int* in_sizes, int n_in,
                              void* d_out, int out_size, void* d_ws, size_t ws_size,
                              hipStream_t stream) {
    const float* Q    = (const float*)d_in[0];
    const float* K    = (const float*)d_in[1];
    const float* V    = (const float*)d_in[2];
    const int*   mask = (const int*)d_in[3];
    const float* Wq   = (const float*)d_in[4];
    const float* bq   = (const float*)d_in[5];
    const float* Wk   = (const float*)d_in[6];
    const float* bk   = (const float*)d_in[7];
    const float* Wv   = (const float*)d_in[8];
    const float* bv   = (const float*)d_in[9];

    float* out      = (float*)d_out;                              // [B,S,Dv]
    float* attn_out = out + (long long)B_N * S_N * DV_N;          // [B,S,S] (k-major rows over q)

    // Workspace layout (~158 MB peak).
    unsigned short* Qbf  = (unsigned short*)d_ws;
    unsigned short* Kbf  = Qbf + (long long)B_N * S_N * D_N;
    unsigned short* attn_bf = Qbf;  // overlay: Qbf/Kbf dead after scores GEMM
    unsigned short* Vbf  = Kbf + (long long)B_N * S_N * D_N;
    unsigned short* Wqbf = Vbf + (long long)B_N * S_N * D_N;
    unsigned short* Wkbf = Wqbf + (long long)A_N * D_N;
    unsigned short* Wvbf = Wkbf + (long long)A_N * D_N;
    unsigned short* Qp   = Wvbf + (long long)DV_N * D_N;
    unsigned short* Kp   = Qp + (long long)B_N * S_N * A_N;
    unsigned short* WVt  = Kp + (long long)B_N * S_N * A_N;
    unsigned int*   mpT  = (unsigned int*)(WVt + (long long)B_N * DV_N * S_N); // 4 MB

    const float scale = 0.044194173824159216f;  // 1/sqrt(512)

    // 0) bit-pack transposed mask (independent; overlaps nothing it needs)
    pack_maskT<<<dim3(S_N / 128, S_N / 64, B_N), dim3(256), 0, stream>>>(mask, mpT);

    // 1) fp32 -> bf16 conversions
    {
        long long nQ = (long long)B_N * S_N * D_N;
        long long nW = (long long)A_N * D_N;
        int n4;
        n4 = (int)(nQ / 4);
        cvt_f32_bf16<<<dim3((n4 + 255) / 256), dim3(256), 0, stream>>>(Q, Qbf, n4);
        cvt_f32_bf16<<<dim3((n4 + 255) / 256), dim3(256), 0, stream>>>(K, Kbf, n4);
        cvt_f32_bf16<<<dim3((n4 + 255) / 256), dim3(256), 0, stream>>>(V, Vbf, n4);
        n4 = (int)(nW / 4);
        cvt_f32_bf16<<<dim3((n4 + 255) / 256), dim3(256), 0, stream>>>(Wq, Wqbf, n4);
        cvt_f32_bf16<<<dim3((n4 + 255) / 256), dim3(256), 0, stream>>>(Wk, Wkbf, n4);
        cvt_f32_bf16<<<dim3((n4 + 255) / 256), dim3(256), 0, stream>>>(Wv, Wvbf, n4);
    }

    // 2) Qp = Q @ Wq^T + bq   [16384 x 512] bf16
    gemm_nt<0><<<dim3(A_N / 128, (B_N * S_N) / 128, 1), dim3(256), 0, stream>>>(
        Qbf, Wqbf, (void*)Qp, bq, B_N * S_N, A_N, D_N, 0, 0, 0, 1.0f);
    // 3) Kp = K @ Wk^T + bk
    gemm_nt<0><<<dim3(A_N / 128, (B_N * S_N) / 128, 1), dim3(256), 0, stream>>>(
        Kbf, Wkbf, (void*)Kp, bk, B_N * S_N, A_N, D_N, 0, 0, 0, 1.0f);
    // 4) WVt[b] = (V[b] @ Wv^T + bv)^T : M=Dv rows, N=S cols
    gemm_nt<1><<<dim3(S_N / 128, DV_N / 128, B_N), dim3(256), 0, stream>>>(
        Wvbf, Vbf, (void*)WVt, bv, DV_N, S_N, D_N,
        0, (long long)S_N * D_N, (long long)DV_N * S_N, 1.0f);
    // 5) scores^T[b,k,q] = (Kp[b,k,:].Qp[b,q,:])*scale -> d_out attn region (mask in softmax)
    gemm_nt<2><<<dim3(S_N / 128, S_N / 128, B_N), dim3(256), 0, stream>>>(
        Kp, Qp, (void*)attn_out, nullptr, S_N, S_N, A_N,
        (long long)S_N * A_N, (long long)S_N * A_N, (long long)S_N * S_N, scale);
    // 6) row softmax over q (in place, masked) + bf16 copy
    softmax_rows<<<dim3(B_N * S_N), dim3(256), 0, stream>>>(attn_out, attn_bf, mpT);
    // 7) selfOutput[b,k,v] = sum_q attn[b,k,q] * WVt[b,v,q]
    gemm_nt<3><<<dim3(DV_N / 128, S_N / 128, B_N), dim3(256), 0, stream>>>(
        attn_bf, WVt, (void*)out, nullptr, S_N, DV_N, S_N,
        (long long)S_N * S_N, (long long)DV_N * S_N, (long long)S_N * DV_N, 1.0f);
}

// Round 3
// 677.688 us; speedup vs baseline: 1.0187x; 1.0131x over previous
//
#include <hip/hip_runtime.h>
#include <stdint.h>

// Problem constants (fixed by setup_inputs)
#define B_N   8
#define S_N   2048
#define D_N   1024
#define A_N   512
#define DV_N  512

typedef __attribute__((ext_vector_type(8))) short bf16x8;
typedef __attribute__((ext_vector_type(4))) float f32x4;

__device__ __forceinline__ unsigned short f2bf(float x) {
    union { float f; unsigned int u; } v; v.f = x;
    return (unsigned short)((v.u + 0x7fffu + ((v.u >> 16) & 1u)) >> 16);
}
__device__ __forceinline__ float bf2f(unsigned short h) {
    union { unsigned int u; float f; } v; v.u = ((unsigned int)h) << 16;
    return v.f;
}

// z-indexed triple fp32->bf16 converter (used for Q,K,V and for the 3 weights)
__global__ void cvt3_f32_bf16(const float* __restrict__ s0, const float* __restrict__ s1,
                              const float* __restrict__ s2,
                              unsigned short* __restrict__ d0, unsigned short* __restrict__ d1,
                              unsigned short* __restrict__ d2, int n4) {
    const float* s = (blockIdx.z == 0) ? s0 : (blockIdx.z == 1) ? s1 : s2;
    unsigned short* d = (blockIdx.z == 0) ? d0 : (blockIdx.z == 1) ? d1 : d2;
    int i = blockIdx.x * blockDim.x + threadIdx.x;
    if (i >= n4) return;
    float4 v = ((const float4*)s)[i];
    ushort4 o;
    o.x = f2bf(v.x); o.y = f2bf(v.y); o.z = f2bf(v.z); o.w = f2bf(v.w);
    ((ushort4*)d)[i] = o;
}

__global__ void zero_f32(float* __restrict__ p, int n) {
    int i = blockIdx.x * blockDim.x + threadIdx.x;
    if (i < n) p[i] = 0.0f;
}

__device__ __forceinline__ void gld_lds16(const void* g, void* l) {
    __builtin_amdgcn_global_load_lds(
        (const __attribute__((address_space(1))) unsigned int*)g,
        (__attribute__((address_space(3))) unsigned int*)l, 16, 0, 0);
}

// Bit-pack the transposed mask: mpT[b][k][w] bit q%32 of word q/32 = mask[b][q][k].
__global__ __launch_bounds__(256) void pack_maskT(const int* __restrict__ mask,
                                                  unsigned int* __restrict__ mpT) {
    __shared__ int tile[64 * 129];
    const int b  = blockIdx.z;
    const int q0 = blockIdx.y * 64;
    const int k0 = blockIdx.x * 128;
    const int tid = threadIdx.x;
    const long long base = (long long)b * S_N * S_N;
#pragma unroll
    for (int it = 0; it < 8; ++it) {
        int c = it * 256 + tid;
        int row  = c >> 5;
        int col4 = (c & 31) * 4;
        int4 v = *(const int4*)&mask[base + (long long)(q0 + row) * S_N + k0 + col4];
        int* d = &tile[row * 129 + col4];
        d[0] = v.x; d[1] = v.y; d[2] = v.z; d[3] = v.w;
    }
    __syncthreads();
    const int wave = tid >> 6, lane = tid & 63;
#pragma unroll
    for (int kk = 0; kk < 32; ++kk) {
        const int k = wave * 32 + kk;
        const int v = tile[lane * 129 + k];
        const unsigned long long bal = __ballot(v != 0);
        if (lane == 0) {
            unsigned int* o = &mpT[(long long)(b * S_N + k0 + k) * 64 + (q0 >> 5)];
            o[0] = (unsigned int)bal;
            o[1] = (unsigned int)(bal >> 32);
        }
    }
}

// NT GEMM: C[m,n] = sum_k A[m,k]*B[n,k]
// MODE 0: bf16 out + bias[col]; dual-weight: blockIdx.y>=128 -> B2/bias2 (fused Q&K proj)
// MODE 1: bf16 out + bias[row]              (WV^T projection, batched)
// MODE 2: e = exp(acc*scale) masked; bf16 out; rowsum atomics   (scores^T)
// MODE 3: f32 out, row-scaled by 1/rowsum   (final attn @ WV)
template <int MODE>
__global__ __launch_bounds__(256) void gemm_nt(
    const unsigned short* __restrict__ A, const unsigned short* __restrict__ B,
    const unsigned short* __restrict__ B2,
    void* __restrict__ C, const float* __restrict__ bias, const float* __restrict__ bias2,
    const unsigned int* __restrict__ mpT, float* __restrict__ rowsum,
    int M, int N, int K,
    long long sA, long long sB, long long sC, float scale)
{
    __shared__ __align__(16) unsigned short As[128 * 32];
    __shared__ __align__(16) unsigned short Bs[128 * 32];

    const int tid  = threadIdx.x;
    const int wave = tid >> 6;
    const int lane = tid & 63;
    const int lrow = lane & 15;
    const int quad = lane >> 4;
    const int wm = wave & 1;
    const int wn = wave >> 1;
    const int b  = blockIdx.z;
    const int m0 = blockIdx.y * 128;
    const int n0 = blockIdx.x * 128;

    const unsigned short* Ab = A + (long long)b * sA;
    const unsigned short* Bsel = (MODE == 0 && blockIdx.y >= 128) ? B2 : B;
    const unsigned short* Bb = Bsel + (long long)b * sB;
    const float* bias_s = (MODE == 0 && blockIdx.y >= 128) ? bias2 : bias;

    f32x4 acc[4][4];
#pragma unroll
    for (int i = 0; i < 4; ++i)
#pragma unroll
        for (int j = 0; j < 4; ++j) acc[i][j] = (f32x4){0.f, 0.f, 0.f, 0.f};

    const int srow = lane >> 2;        // row within 16-row segment
    const int scol = (lane & 3) * 8;   // k-element offset (8 bf16 = 16B)

    for (int kt = 0; kt < K; kt += 32) {
#pragma unroll
        for (int t = 0; t < 2; ++t) {
            const int seg = t * 4 + wave;
            const unsigned short* ga =
                Ab + (long long)(m0 + seg * 16 + srow) * K + kt + scol;
            gld_lds16(ga, &As[seg * 16 * 32]);
            const unsigned short* gb =
                Bb + (long long)(n0 + seg * 16 + srow) * K + kt + scol;
            gld_lds16(gb, &Bs[seg * 16 * 32]);
        }
        __syncthreads();

        bf16x8 af[4], bfr[4];
#pragma unroll
        for (int i = 0; i < 4; ++i)
            af[i] = *(const bf16x8*)&As[(wm * 64 + i * 16 + lrow) * 32 + quad * 8];
#pragma unroll
        for (int j = 0; j < 4; ++j)
            bfr[j] = *(const bf16x8*)&Bs[(wn * 64 + j * 16 + lrow) * 32 + quad * 8];
#pragma unroll
        for (int i = 0; i < 4; ++i)
#pragma unroll
            for (int j = 0; j < 4; ++j)
                acc[i][j] = __builtin_amdgcn_mfma_f32_16x16x32_bf16(
                    af[i], bfr[j], acc[i][j], 0, 0, 0);
        __syncthreads();
    }

    // Epilogue. C/D layout (verified): col = lane&15, row = quad*4 + reg.
    if (MODE == 0 || MODE == 1) {
#pragma unroll
        for (int i = 0; i < 4; ++i) {
            const int rowb = m0 + wm * 64 + i * 16 + quad * 4;
#pragma unroll
            for (int j = 0; j < 4; ++j) {
                const int col = n0 + wn * 64 + j * 16 + lrow;
#pragma unroll
                for (int r = 0; r < 4; ++r) {
                    const int row = rowb + r;
                    float v = acc[i][j][r];
                    v += (MODE == 0) ? bias_s[col] : bias_s[row];
                    (((unsigned short*)C) + (long long)b * sC)
                        [(long long)row * N + col] = f2bf(v);
                }
            }
        }
    } else if (MODE == 2) {
        unsigned short* Cb = ((unsigned short*)C) + (long long)b * sC;
        const unsigned int* mpb = mpT + ((long long)b * S_N) * 64;
        float* rs = rowsum + (long long)b * S_N;
#pragma unroll
        for (int i = 0; i < 4; ++i) {
#pragma unroll
            for (int r = 0; r < 4; ++r) {
                const int row = m0 + wm * 64 + i * 16 + quad * 4 + r;
                const unsigned int* mpr = mpb + (long long)row * 64;
                float rsum = 0.0f;
#pragma unroll
                for (int j = 0; j < 4; ++j) {
                    const int col = n0 + wn * 64 + j * 16 + lrow;
                    const float v = acc[i][j][r] * scale;
                    const unsigned int w = mpr[col >> 5];
                    const float e = ((w >> (col & 31)) & 1u) ? 0.0f : __expf(v);
                    const unsigned short h = f2bf(e);
                    Cb[(long long)row * S_N + col] = h;
                    rsum += bf2f(h);   // sum the rounded values for consistency
                }
                rsum += __shfl_xor(rsum, 1);
                rsum += __shfl_xor(rsum, 2);
                rsum += __shfl_xor(rsum, 4);
                rsum += __shfl_xor(rsum, 8);
                if (lrow == 0) atomicAdd(&rs[row], rsum);
            }
        }
    } else {  // MODE 3
        float* Cb = ((float*)C) + (long long)b * sC;
        const float* rs = rowsum + (long long)b * S_N;
#pragma unroll
        for (int i = 0; i < 4; ++i) {
#pragma unroll
            for (int r = 0; r < 4; ++r) {
                const int row = m0 + wm * 64 + i * 16 + quad * 4 + r;
                const float inv = 1.0f / rs[row];
#pragma unroll
                for (int j = 0; j < 4; ++j) {
                    const int col = n0 + wn * 64 + j * 16 + lrow;
                    Cb[(long long)row * N + col] = acc[i][j][r] * inv;
                }
            }
        }
    }
}

// attn[row][q] = bf16e[row][q] / rowsum[row]  (fp32 write to d_out attn region)
__global__ __launch_bounds__(256) void normalize_rows(
    const unsigned short* __restrict__ ebf, const float* __restrict__ rowsum,
    float* __restrict__ attn)
{
    const long long row = blockIdx.x;
    const float inv = 1.0f / rowsum[row];
    const ushort4* src = (const ushort4*)(ebf + row * S_N);
    float4* dst = (float4*)(attn + row * S_N);
    const int tid = threadIdx.x;
#pragma unroll
    for (int t = 0; t < 2; ++t) {
        ushort4 h = src[tid + t * 256];
        float4 o;
        o.x = bf2f(h.x) * inv;
        o.y = bf2f(h.y) * inv;
        o.z = bf2f(h.z) * inv;
        o.w = bf2f(h.w) * inv;
        dst[tid + t * 256] = o;
    }
}

extern "C" void kernel_launch(void* const* d_in, const int* in_sizes, int n_in,
                              void* d_out, int out_size, void* d_ws, size_t ws_size,
                              hipStream_t stream) {
    const float* Q    = (const float*)d_in[0];
    const float* K    = (const float*)d_in[1];
    const float* V    = (const float*)d_in[2];
    const int*   mask = (const int*)d_in[3];
    const float* Wq   = (const float*)d_in[4];
    const float* bq   = (const float*)d_in[5];
    const float* Wk   = (const float*)d_in[6];
    const float* bk   = (const float*)d_in[7];
    const float* Wv   = (const float*)d_in[8];
    const float* bv   = (const float*)d_in[9];

    float* out      = (float*)d_out;                              // [B,S,Dv]
    float* attn_out = out + (long long)B_N * S_N * DV_N;          // [B,S,S]

    // Workspace layout. Qbf||Kbf contiguous (fused QK proj reads rows 0..32767);
    // attn_bf (67.1MB, bf16 e-values) overlays Qbf+Kbf after the projections.
    unsigned short* Qbf  = (unsigned short*)d_ws;
    unsigned short* Kbf  = Qbf + (long long)B_N * S_N * D_N;
    unsigned short* attn_bf = Qbf;  // overlay
    unsigned short* Vbf  = Kbf + (long long)B_N * S_N * D_N;
    unsigned short* Wqbf = Vbf + (long long)B_N * S_N * D_N;
    unsigned short* Wkbf = Wqbf + (long long)A_N * D_N;
    unsigned short* Wvbf = Wkbf + (long long)A_N * D_N;
    unsigned short* Qp   = Wvbf + (long long)DV_N * D_N;   // Qp||Kp contiguous
    unsigned short* Kp   = Qp + (long long)B_N * S_N * A_N;
    unsigned short* WVt  = Kp + (long long)B_N * S_N * A_N;
    unsigned int*   mpT  = (unsigned int*)(WVt + (long long)B_N * DV_N * S_N); // 4 MB
    float*          rowsum = (float*)(mpT + (long long)B_N * S_N * 64);        // 64 KB

    const float scale = 0.044194173824159216f;  // 1/sqrt(512)

    // 0) zero rowsum (ws is poisoned each call) + pack transposed mask bits
    zero_f32<<<dim3((B_N * S_N) / 256), dim3(256), 0, stream>>>(rowsum, B_N * S_N);
    pack_maskT<<<dim3(S_N / 128, S_N / 64, B_N), dim3(256), 0, stream>>>(mask, mpT);

    // 1) fp32 -> bf16: Q,K,V in one dispatch; 3 weights in one dispatch
    {
        int n4 = (int)((long long)B_N * S_N * D_N / 4);
        cvt3_f32_bf16<<<dim3((n4 + 255) / 256, 1, 3), dim3(256), 0, stream>>>(
            Q, K, V, Qbf, Kbf, Vbf, n4);
        int w4 = (int)((long long)A_N * D_N / 4);
        cvt3_f32_bf16<<<dim3((w4 + 255) / 256, 1, 3), dim3(256), 0, stream>>>(
            Wq, Wk, Wv, Wqbf, Wkbf, Wvbf, w4);
    }

    // 2) fused Q&K projections: rows 0..16383 -> Qp (Wq,bq), 16384..32767 -> Kp (Wk,bk)
    gemm_nt<0><<<dim3(A_N / 128, (2 * B_N * S_N) / 128, 1), dim3(256), 0, stream>>>(
        Qbf, Wqbf, Wkbf, (void*)Qp, bq, bk, nullptr, nullptr,
        2 * B_N * S_N, A_N, D_N, 0, 0, 0, 1.0f);
    // 3) WVt[b] = (V[b] @ Wv^T + bv)^T : M=Dv rows, N=S cols
    gemm_nt<1><<<dim3(S_N / 128, DV_N / 128, B_N), dim3(256), 0, stream>>>(
        Wvbf, Vbf, nullptr, (void*)WVt, bv, nullptr, nullptr, nullptr,
        DV_N, S_N, D_N, 0, (long long)S_N * D_N, (long long)DV_N * S_N, 1.0f);
    // 4) e[b,k,q] = exp(scale*Kp.Qp) masked -> bf16 attn_bf; rowsum atomics
    gemm_nt<2><<<dim3(S_N / 128, S_N / 128, B_N), dim3(256), 0, stream>>>(
        Kp, Qp, nullptr, (void*)attn_bf, nullptr, nullptr, mpT, rowsum,
        S_N, S_N, A_N, (long long)S_N * A_N, (long long)S_N * A_N,
        (long long)S_N * S_N, scale);
    // 5) attn fp32 = e / rowsum -> d_out attn region
    normalize_rows<<<dim3(B_N * S_N), dim3(256), 0, stream>>>(attn_bf, rowsum, attn_out);
    // 6) selfOutput[b,k,v] = (sum_q e[b,k,q] * WVt[b,v,q]) / rowsum[b,k]
    gemm_nt<3><<<dim3(DV_N / 128, S_N / 128, B_N), dim3(256), 0, stream>>>(
        attn_bf, WVt, nullptr, (void*)out, nullptr, nullptr, nullptr, rowsum,
        S_N, DV_N, S_N, (long long)S_N * S_N, (long long)DV_N * S_N,
        (long long)S_N * DV_N, 1.0f);
}